// Round 9
// baseline (196.088 us; speedup 1.0000x reference)
//
#include <hip/hip_runtime.h>
#include <hip/hip_bf16.h>

// Problem constants
#define NN 384
#define CUTOFF2 144.0f
#define GAMMA 1.7777778f   // (16/12)^2

// packed B-frag layout per layer (u32 units): [W1b 8192 | We 2048 | W2 8192 | C1 8192]
#define PK_L 26624
#define PK_WE 8192
#define PK_W2 10240
#define PK_C1 18432

#define STG_F32 1152                      // 32 rows x 36 f32 per-wave stage
#define EDGE_SMEM ((PK_L + 8*STG_F32)*4)  // 143360 B -> 1 block/CU

// ws byte offsets
#define O_XA 0
#define O_XB 4608
#define O_H 9216
#define O_A 205824
#define O_AGG 402432
#define O_HBF 599040
#define O_EREC 697344      // 384*384*16
#define O_UNITS 3056640
#define O_UCNT 3075072     // 3 ints, zeroed by hipMemsetAsync
#define O_MEAN 3075136     // 3 floats
#define O_PK 3075200

typedef __bf16 bf16x8 __attribute__((ext_vector_type(8)));
typedef float f32x4 __attribute__((ext_vector_type(4)));

union ER { struct { float dx, dy, dz; unsigned j; } e; uint4 u4; };

__device__ __forceinline__ unsigned short f2bf(float f){
  unsigned u = __float_as_uint(f);
  return (unsigned short)((u + 0x7fffu + ((u >> 16) & 1u)) >> 16);  // RNE
}
__device__ __forceinline__ unsigned pk2(float a, float b){
  return ((unsigned)f2bf(b) << 16) | f2bf(a);
}
__device__ __forceinline__ float silu(float x){ return x / (1.0f + __expf(-x)); }

// ---- weight packing into MFMA B-frag order (one element per thread)
__device__ __forceinline__ void pack_one(int t, const float* __restrict__ eW1,
                                         const float* __restrict__ eW2,
                                         const float* __restrict__ cW1,
                                         unsigned* __restrict__ pk){
  int layer = t / PK_L, r = t % PK_L;
  const float* src; int fr; int isWe = 0;
  if (r < PK_WE)        { fr = r;          src = eW1 + (layer*272 + 128)*128; }
  else if (r < PK_W2)   { fr = r - PK_WE;  src = eW1 + (layer*272 + 256)*128; isWe = 1; }
  else if (r < PK_C1)   { fr = r - PK_W2;  src = eW2 + layer*128*128; }
  else                  { fr = r - PK_C1;  src = cW1 + layer*128*128; }
  int tp = fr & 3, l = (fr >> 2) & 63, nc = fr >> 8;
  int n, k;
  if (!isWe) { n = nc >> 2; int c = nc & 3; k = c*32 + ((l>>4)<<3) + 2*tp; }
  else       { n = nc;                      k = ((l>>4)<<3) + 2*tp; }
  int nn = n*16 + (l & 15);
  float w0, w1;
  if (isWe) { w0 = (k < 16)   ? src[k*128+nn]     : 0.f;
              w1 = (k+1 < 16) ? src[(k+1)*128+nn] : 0.f; }
  else      { w0 = src[k*128+nn]; w1 = src[(k+1)*128+nn]; }
  pk[t] = ((unsigned)f2bf(w1) << 16) | f2bf(w0);
}

// ---- scan: 3 rows/block, 128 threads/row; mean-free (diffs are translation-invariant)
__device__ __forceinline__ void scan3(
    int row, int rsel, int o, bool v, const float* __restrict__ x,
    uint4* __restrict__ erec, int* __restrict__ units, int* __restrict__ ucntSlot,
    int* scn){
  int* scnt  = scn + rsel*2;
  int* sbase = scnt + 1;
  if (v && o == 0) *scnt = 0;
  __syncthreads();
  if (v) {
    float xi0 = x[row*3], xi1 = x[row*3+1], xi2 = x[row*3+2];
    for (int j = o; j < 384; j += 128) {
      float d0 = xi0-x[j*3], d1 = xi1-x[j*3+1], d2 = xi2-x[j*3+2];
      float dd = d0*d0 + d1*d1 + d2*d2;
      bool msk = ((dd < CUTOFF2) && (j != row)) || (j == row-1) || (j == row+1);
      if (msk) {
        int ss = atomicAdd(scnt, 1);
        ER er; er.e.dx = d0; er.e.dy = d1; er.e.dz = d2; er.e.j = (unsigned)j;
        erec[row*384 + ss] = er.u4;
      }
    }
  }
  __syncthreads();
  if (v) {
    int cnt = *scnt;
    int p = (32 - (cnt & 31)) & 31;
    if (o < p) {
      ER er; er.e.dx = 0.f; er.e.dy = 0.f; er.e.dz = 0.f; er.e.j = (unsigned)row;
      erec[row*384 + cnt + o] = er.u4;
    }
    if (o == 0) *sbase = atomicAdd(ucntSlot, (cnt + 31) >> 5);
  }
  __syncthreads();
  if (v) {
    int cnt = *scnt, nu = (cnt + 31) >> 5;
    if (o < nu) {
      int nv = cnt - (o << 5); if (nv > 32) nv = 32;
      units[*sbase + o] = row | (o << 9) | (nv << 13);
    }
  }
}

// ---- K1: pack (blocks 0..155) | mean (156) | proj+seed+scan0 (157..284, 3 rows each)
__global__ __launch_bounds__(512) void k_init(
    const float* __restrict__ eW1, const float* __restrict__ eW2,
    const float* __restrict__ cW1, unsigned* __restrict__ pk,
    const float* __restrict__ anchor, const float* __restrict__ z,
    const float* __restrict__ pW, const float* __restrict__ pbias,
    const float* __restrict__ eb1, float* __restrict__ h,
    unsigned short* __restrict__ hbf, float* __restrict__ A,
    float* __restrict__ agg, float* __restrict__ xB, float* __restrict__ meanw,
    uint4* __restrict__ erec, int* __restrict__ units, int* __restrict__ ucnt0){
  const int b = blockIdx.x, tid = threadIdx.x;
  if (b < 156) { pack_one(b*512 + tid, eW1, eW2, cW1, pk); return; }
  if (b == 156) {
    __shared__ float ssum[3];
    if (tid < 3) ssum[tid] = 0.f;
    __syncthreads();
    if (tid < 384) {
      atomicAdd(&ssum[0], anchor[tid*3]);
      atomicAdd(&ssum[1], anchor[tid*3+1]);
      atomicAdd(&ssum[2], anchor[tid*3+2]);
    }
    __syncthreads();
    if (tid < 3) meanw[tid] = ssum[tid]*(1.f/384.f);
    return;
  }
  __shared__ float wt[8192];          // 32KB weight tile
  __shared__ float sh[3][128];
  __shared__ float sz[3][64];
  __shared__ int scn[6];
  const int o = tid & 127, rsel = tid >> 7;
  const int row = (b - 157)*3 + rsel;
  const bool v = rsel < 3;
  if (v) {
    if (o < 64) sz[rsel][o] = z[row*64 + o];
    agg[row*128 + o] = 0.f;
    if (o < 3) xB[row*3 + o] = anchor[row*3 + o];   // uncentered seed
  }
  // stage pW (64x128 = exactly one tile)
  {
    const float4* g = (const float4*)pW;
    #pragma unroll
    for (int i = 0; i < 4; ++i) ((float4*)wt)[tid + 512*i] = g[tid + 512*i];
  }
  __syncthreads();
  float a0=0,a1=0,a2=0,a3=0;
  if (v) {
    #pragma unroll 16
    for (int kk = 0; kk < 64; kk += 4) {
      a0 += sz[rsel][kk]  *wt[kk*128+o];     a1 += sz[rsel][kk+1]*wt[(kk+1)*128+o];
      a2 += sz[rsel][kk+2]*wt[(kk+2)*128+o]; a3 += sz[rsel][kk+3]*wt[(kk+3)*128+o];
    }
  }
  __syncthreads();
  if (v) {
    float hh = pbias[o] + (a0+a1)+(a2+a3);
    sh[rsel][o] = hh; h[row*128 + o] = hh; hbf[row*128 + o] = f2bf(hh);
  }
  __syncthreads();
  // A = eb1 + sh @ W1a (2 tiles of eW1 layer0 rows 0..127)
  a0=a1=a2=a3=0;
  for (int t = 0; t < 2; ++t) {
    const float4* g = (const float4*)(eW1 + t*8192);
    #pragma unroll
    for (int i = 0; i < 4; ++i) ((float4*)wt)[tid + 512*i] = g[tid + 512*i];
    __syncthreads();
    if (v) {
      const float* s = &sh[rsel][t*64];
      #pragma unroll 16
      for (int kk = 0; kk < 64; kk += 4) {
        a0 += s[kk]  *wt[kk*128+o];     a1 += s[kk+1]*wt[(kk+1)*128+o];
        a2 += s[kk+2]*wt[(kk+2)*128+o]; a3 += s[kk+3]*wt[(kk+3)*128+o];
      }
    }
    __syncthreads();
  }
  if (v) A[row*128 + o] = eb1[o] + (a0+a1)+(a2+a3);
  scan3(row, rsel, o, v, anchor, erec, units, ucnt0, scn);
}

// ---- node: 128 blocks x 3 rows; LDS-tiled weight matvecs; + scan(next layer)
__global__ __launch_bounds__(512) void k_node(
    const float* __restrict__ nW1l, const float* __restrict__ nb1l,
    const float* __restrict__ nW2l, const float* __restrict__ nb2l,
    const float* __restrict__ eW1a, const float* __restrict__ eb1a,
    float* __restrict__ h, unsigned short* __restrict__ hbf,
    float* __restrict__ agg, float* __restrict__ A,
    const float* __restrict__ xsrc, float* __restrict__ xdst,
    const float* __restrict__ meanp,
    uint4* __restrict__ erec, int* __restrict__ units, int* __restrict__ ucntSlot){
  __shared__ float wt[8192];
  __shared__ float sh[3][128], sg[3][128], st[3][128], shn[3][128];
  __shared__ int scn[6];
  const int tid = threadIdx.x, o = tid & 127, rsel = tid >> 7;
  const int row = blockIdx.x*3 + rsel;
  const bool v = rsel < 3;
  if (v) {
    sh[rsel][o] = h[row*128 + o];
    sg[rsel][o] = agg[row*128 + o];
    agg[row*128 + o] = 0.f;
    if (o < 3) {
      float m = meanp ? meanp[o] : 0.f;
      xdst[row*3 + o] = xsrc[row*3 + o] - m;
    }
  }
  __syncthreads();
  // matvec1: [h|agg] @ nW1 (256 rows = 4 tiles)
  float a0=0,a1=0,a2=0,a3=0;
  for (int t = 0; t < 4; ++t) {
    const float4* g = (const float4*)(nW1l + t*8192);
    #pragma unroll
    for (int i = 0; i < 4; ++i) ((float4*)wt)[tid + 512*i] = g[tid + 512*i];
    __syncthreads();
    if (v) {
      const float* s = (t < 2) ? &sh[rsel][t*64] : &sg[rsel][(t-2)*64];
      #pragma unroll 16
      for (int kk = 0; kk < 64; kk += 4) {
        a0 += s[kk]  *wt[kk*128+o];     a1 += s[kk+1]*wt[(kk+1)*128+o];
        a2 += s[kk+2]*wt[(kk+2)*128+o]; a3 += s[kk+3]*wt[(kk+3)*128+o];
      }
    }
    __syncthreads();
  }
  if (v) st[rsel][o] = silu(nb1l[o] + (a0+a1)+(a2+a3));
  __syncthreads();
  // matvec2: st @ nW2 (2 tiles); h_new = h + . + nb2
  a0=a1=a2=a3=0;
  for (int t = 0; t < 2; ++t) {
    const float4* g = (const float4*)(nW2l + t*8192);
    #pragma unroll
    for (int i = 0; i < 4; ++i) ((float4*)wt)[tid + 512*i] = g[tid + 512*i];
    __syncthreads();
    if (v) {
      const float* s = &st[rsel][t*64];
      #pragma unroll 16
      for (int kk = 0; kk < 64; kk += 4) {
        a0 += s[kk]  *wt[kk*128+o];     a1 += s[kk+1]*wt[(kk+1)*128+o];
        a2 += s[kk+2]*wt[(kk+2)*128+o]; a3 += s[kk+3]*wt[(kk+3)*128+o];
      }
    }
    __syncthreads();
  }
  if (v) {
    float hn = sh[rsel][o] + nb2l[o] + (a0+a1)+(a2+a3);
    h[row*128 + o] = hn; hbf[row*128 + o] = f2bf(hn); shn[rsel][o] = hn;
  }
  __syncthreads();
  // matvec3: h_new @ W1a(next layer) (2 tiles) -> A
  a0=a1=a2=a3=0;
  for (int t = 0; t < 2; ++t) {
    const float4* g = (const float4*)(eW1a + t*8192);
    #pragma unroll
    for (int i = 0; i < 4; ++i) ((float4*)wt)[tid + 512*i] = g[tid + 512*i];
    __syncthreads();
    if (v) {
      const float* s = &shn[rsel][t*64];
      #pragma unroll 16
      for (int kk = 0; kk < 64; kk += 4) {
        a0 += s[kk]  *wt[kk*128+o];     a1 += s[kk+1]*wt[(kk+1)*128+o];
        a2 += s[kk+2]*wt[(kk+2)*128+o]; a3 += s[kk+3]*wt[(kk+3)*128+o];
      }
    }
    __syncthreads();
  }
  if (v) A[row*128 + o] = eb1a[o] + (a0+a1)+(a2+a3);
  scan3(row, rsel, o, v, xsrc, erec, units, ucntSlot, scn);
}

// ---- C-layout -> A-frag transpose via per-wave f32 LDS pad (wave-private, no fences)
#define TRANSFORM(VA, VB, FA, FB)                                              \
  _Pragma("unroll")                                                            \
  for (int c = 0; c < 4; ++c) {                                                \
    _Pragma("unroll")                                                          \
    for (int tl = 0; tl < 2; ++tl) {                                           \
      int t = 2*c + tl;                                                        \
      _Pragma("unroll")                                                        \
      for (int r = 0; r < 4; ++r) {                                            \
        stg[(quad*4 + r)*36 + tl*16 + col0] = VA[t][r];                        \
        stg[(16 + quad*4 + r)*36 + tl*16 + col0] = VB[t][r];                   \
      }                                                                        \
    }                                                                          \
    float4 lo = *(const float4*)(stg + col0*36 + quad*8);                      \
    float4 hi = *(const float4*)(stg + col0*36 + quad*8 + 4);                  \
    FA[c].u = make_uint4(pk2(lo.x,lo.y), pk2(lo.z,lo.w),                       \
                         pk2(hi.x,hi.y), pk2(hi.z,hi.w));                      \
    float4 lo2 = *(const float4*)(stg + (16 + col0)*36 + quad*8);              \
    float4 hi2 = *(const float4*)(stg + (16 + col0)*36 + quad*8 + 4);          \
    FB[c].u = make_uint4(pk2(lo2.x,lo2.y), pk2(lo2.z,lo2.w),                   \
                         pk2(hi2.x,hi2.y), pk2(hi2.z,hi2.w));                  \
  }

// ---- MFMA edge kernel: wave = one unit (32 same-receiver edges), block-first spread
__global__ __launch_bounds__(512, 1) void k_edge(
    float* __restrict__ x_out, const float* __restrict__ Ag,
    const unsigned short* __restrict__ hbf, const uint4* __restrict__ erec,
    const int* __restrict__ units, const int* __restrict__ Ucnt,
    float* __restrict__ agg, const unsigned* __restrict__ pkl,
    const float* __restrict__ eb2g, const float* __restrict__ cb1g,
    const float* __restrict__ cw2g){
  extern __shared__ unsigned smem[];
  const int tid = threadIdx.x, q = tid & 63, s = tid >> 6;
  const int U = Ucnt[0];
  if (blockIdx.x >= U) return;

  for (int idx = tid; idx < PK_L/4; idx += 512)
    ((uint4*)smem)[idx] = ((const uint4*)pkl)[idx];
  __syncthreads();

  const int col0 = q & 15, quad = q >> 4;
  float eb2v[8], cb1v[8], cw2v[8];
  #pragma unroll
  for (int t = 0; t < 8; ++t) {
    int c = t*16 + col0;
    eb2v[t] = eb2g[c]; cb1v[t] = cb1g[c]; cw2v[t] = cw2g[c];
  }
  float* stg = (float*)(smem + PK_L) + s*STG_F32;
  const f32x4 z4 = {0.f, 0.f, 0.f, 0.f};
  union U8 { uint4 u; bf16x8 v; };

  for (int u = blockIdx.x + 256*s; u < U; u += 2048) {
    const int desc = units[u];
    const int i = desc & 511, b = (desc >> 9) & 15, nvalid = (desc >> 13) & 63;
    float Aval[8];
    #pragma unroll
    for (int t = 0; t < 8; ++t) Aval[t] = Ag[i*128 + t*16 + col0];
    ER e0, e1;
    e0.u4 = erec[i*384 + b*32 + col0];
    e1.u4 = erec[i*384 + b*32 + 16 + col0];
    const int j0 = (int)e0.e.j, j1 = (int)e1.e.j;
    const float d0x = e0.e.dx, d0y = e0.e.dy, d0z = e0.e.dz;
    const float d1x = e1.e.dx, d1y = e1.e.dy, d1z = e1.e.dz;
    const float dd0 = sqrtf(d0x*d0x + d0y*d0y + d0z*d0z);
    const float dd1 = sqrtf(d1x*d1x + d1y*d1y + d1z*d1z);

    U8 ha0[4], ha1[4];
    #pragma unroll
    for (int c = 0; c < 4; ++c) {
      ha0[c].u = *(const uint4*)(hbf + j0*128 + c*32 + quad*8);
      ha1[c].u = *(const uint4*)(hbf + j1*128 + c*32 + quad*8);
    }

    U8 cve0, cve1;
    if (q < 32) {
      #pragma unroll
      for (int tp = 0; tp < 4; ++tp) {
        float k0 = (float)(quad*8 + 2*tp);
        float t00 = dd0 - 0.8f*k0, t01 = dd0 - 0.8f*(k0+1.f);
        float t10 = dd1 - 0.8f*k0, t11 = dd1 - 0.8f*(k0+1.f);
        (&cve0.u.x)[tp] = pk2(__expf(-GAMMA*t00*t00), __expf(-GAMMA*t01*t01));
        (&cve1.u.x)[tp] = pk2(__expf(-GAMMA*t10*t10), __expf(-GAMMA*t11*t11));
      }
    } else { cve0.u = make_uint4(0,0,0,0); cve1.u = make_uint4(0,0,0,0); }

    // GEMM1: m1 = silu(h_j@W1b + e@We + A_i), 32 rows
    f32x4 acc0[8], acc1[8];
    #pragma unroll
    for (int t = 0; t < 8; ++t) { acc0[t] = z4; acc1[t] = z4; }
    #pragma unroll
    for (int t = 0; t < 8; ++t) {
      #pragma unroll
      for (int c = 0; c < 4; ++c) {
        bf16x8 w = *(const bf16x8*)(smem + ((t*4 + c)*64 + q)*4);
        acc0[t] = __builtin_amdgcn_mfma_f32_16x16x32_bf16(ha0[c].v, w, acc0[t], 0, 0, 0);
        acc1[t] = __builtin_amdgcn_mfma_f32_16x16x32_bf16(ha1[c].v, w, acc1[t], 0, 0, 0);
      }
      bf16x8 we = *(const bf16x8*)(smem + PK_WE + (t*64 + q)*4);
      acc0[t] = __builtin_amdgcn_mfma_f32_16x16x32_bf16(cve0.v, we, acc0[t], 0, 0, 0);
      acc1[t] = __builtin_amdgcn_mfma_f32_16x16x32_bf16(cve1.v, we, acc1[t], 0, 0, 0);
    }
    #pragma unroll
    for (int t = 0; t < 8; ++t)
      #pragma unroll
      for (int r = 0; r < 4; ++r) {
        acc0[t][r] = silu(acc0[t][r] + Aval[t]);
        acc1[t][r] = silu(acc1[t][r] + Aval[t]);
      }

    U8 a20[4], a21[4];
    TRANSFORM(acc0, acc1, a20, a21);

    // GEMM2: m = silu(m1@eW2 + eb2)
    f32x4 m0[8], m1v[8];
    #pragma unroll
    for (int t = 0; t < 8; ++t) { m0[t] = z4; m1v[t] = z4; }
    #pragma unroll
    for (int t = 0; t < 8; ++t)
      #pragma unroll
      for (int c = 0; c < 4; ++c) {
        bf16x8 w = *(const bf16x8*)(smem + PK_W2 + ((t*4 + c)*64 + q)*4);
        m0[t] = __builtin_amdgcn_mfma_f32_16x16x32_bf16(a20[c].v, w, m0[t], 0, 0, 0);
        m1v[t] = __builtin_amdgcn_mfma_f32_16x16x32_bf16(a21[c].v, w, m1v[t], 0, 0, 0);
      }
    #pragma unroll
    for (int t = 0; t < 8; ++t) {
      float cs = 0.f;
      #pragma unroll
      for (int r = 0; r < 4; ++r) {
        m0[t][r] = silu(m0[t][r] + eb2v[t]);
        m1v[t][r] = silu(m1v[t][r] + eb2v[t]);
        if (quad*4 + r < nvalid) cs += m0[t][r];
        if (16 + quad*4 + r < nvalid) cs += m1v[t][r];
      }
      cs += __shfl_xor(cs, 16); cs += __shfl_xor(cs, 32);
      if (q < 16) atomicAdd(&agg[i*128 + t*16 + q], cs);
    }

    U8 a30[4], a31[4];
    TRANSFORM(m0, m1v, a30, a31);

    // GEMM3: c1 = silu(m@cW1 + cb1); w_row = c1 . cW2
    f32x4 c30[8], c31[8];
    #pragma unroll
    for (int t = 0; t < 8; ++t) { c30[t] = z4; c31[t] = z4; }
    #pragma unroll
    for (int t = 0; t < 8; ++t)
      #pragma unroll
      for (int c = 0; c < 4; ++c) {
        bf16x8 w = *(const bf16x8*)(smem + PK_C1 + ((t*4 + c)*64 + q)*4);
        c30[t] = __builtin_amdgcn_mfma_f32_16x16x32_bf16(a30[c].v, w, c30[t], 0, 0, 0);
        c31[t] = __builtin_amdgcn_mfma_f32_16x16x32_bf16(a31[c].v, w, c31[t], 0, 0, 0);
      }
    float p0[4], p1[4];
    #pragma unroll
    for (int r = 0; r < 4; ++r) {
      float pa = 0.f, pb = 0.f;
      #pragma unroll
      for (int t = 0; t < 8; ++t) {
        pa += silu(c30[t][r] + cb1v[t]) * cw2v[t];
        pb += silu(c31[t][r] + cb1v[t]) * cw2v[t];
      }
      if (quad*4 + r >= nvalid) pa = 0.f;
      if (16 + quad*4 + r >= nvalid) pb = 0.f;
      p0[r] = pa; p1[r] = pb;
    }
    #pragma unroll
    for (int r = 0; r < 4; ++r)
      #pragma unroll
      for (int off = 1; off < 16; off <<= 1) {
        p0[r] += __shfl_xor(p0[r], off);
        p1[r] += __shfl_xor(p1[r], off);
      }
    float dx0 = 0.f, dx1 = 0.f, dx2 = 0.f;
    #pragma unroll
    for (int r = 0; r < 4; ++r) {
      int el = quad*4 + r;
      float s0 = __shfl(d0x, el), s1 = __shfl(d0y, el), s2 = __shfl(d0z, el);
      if (col0 == 0) { dx0 += p0[r]*s0; dx1 += p0[r]*s1; dx2 += p0[r]*s2; }
      float u0 = __shfl(d1x, el), u1 = __shfl(d1y, el), u2 = __shfl(d1z, el);
      if (col0 == 0) { dx0 += p1[r]*u0; dx1 += p1[r]*u1; dx2 += p1[r]*u2; }
    }
    dx0 += __shfl_xor(dx0, 16); dx0 += __shfl_xor(dx0, 32);
    dx1 += __shfl_xor(dx1, 16); dx1 += __shfl_xor(dx1, 32);
    dx2 += __shfl_xor(dx2, 16); dx2 += __shfl_xor(dx2, 32);
    if (q == 0) {
      atomicAdd(&x_out[i*3 + 0], dx0);
      atomicAdd(&x_out[i*3 + 1], dx1);
      atomicAdd(&x_out[i*3 + 2], dx2);
    }
  }
}

extern "C" void kernel_launch(void* const* d_in, const int* in_sizes, int n_in,
                              void* d_out, int out_size, void* d_ws, size_t ws_size,
                              hipStream_t stream){
  const float* z      = (const float*)d_in[0];
  const float* anchor = (const float*)d_in[1];
  const float* projW  = (const float*)d_in[2];
  const float* projb  = (const float*)d_in[3];
  const float* eW1    = (const float*)d_in[4];
  const float* eb1    = (const float*)d_in[5];
  const float* eW2    = (const float*)d_in[6];
  const float* eb2    = (const float*)d_in[7];
  const float* nW1    = (const float*)d_in[8];
  const float* nb1    = (const float*)d_in[9];
  const float* nW2    = (const float*)d_in[10];
  const float* nb2    = (const float*)d_in[11];
  const float* cW1    = (const float*)d_in[12];
  const float* cb1    = (const float*)d_in[13];
  const float* cW2    = (const float*)d_in[14];
  float* out = (float*)d_out;

  char* w = (char*)d_ws;
  float* xA  = (float*)(w + O_XA);
  float* xB  = (float*)(w + O_XB);
  float* h   = (float*)(w + O_H);
  float* A   = (float*)(w + O_A);
  float* agg = (float*)(w + O_AGG);
  unsigned short* hbf = (unsigned short*)(w + O_HBF);
  uint4* erec = (uint4*)(w + O_EREC);
  int* units = (int*)(w + O_UNITS);
  int* ucnt  = (int*)(w + O_UCNT);
  float* meanw = (float*)(w + O_MEAN);
  unsigned* pk = (unsigned*)(w + O_PK);

  hipFuncSetAttribute((const void*)k_edge, hipFuncAttributeMaxDynamicSharedMemorySize, EDGE_SMEM);

  hipMemsetAsync(ucnt, 0, 12, stream);
  k_init<<<285, 512, 0, stream>>>(eW1, eW2, cW1, pk, anchor, z, projW, projb,
                                  eb1, h, hbf, A, agg, xB, meanw, erec, units, ucnt + 0);
  // layer 0: edges (from anchor-geometry), accumulate into xB (seeded = anchor)
  k_edge<<<256, 512, EDGE_SMEM, stream>>>(xB, A, hbf, erec, units, ucnt + 0,
                                          agg, pk, eb2, cb1, cW2);
  k_node<<<128, 512, 0, stream>>>(nW1, nb1, nW2, nb2, eW1 + 272*128, eb1 + 128,
                                  h, hbf, agg, A, xB, xA, (const float*)nullptr,
                                  erec, units, ucnt + 1);
  // layer 1: edges from xB geometry, accumulate into xA (seeded = xB)
  k_edge<<<256, 512, EDGE_SMEM, stream>>>(xA, A, hbf, erec, units, ucnt + 1,
                                          agg, pk + PK_L, eb2 + 128, cb1 + 128, cW2 + 128);
  k_node<<<128, 512, 0, stream>>>(nW1 + 256*128, nb1 + 128, nW2 + 128*128, nb2 + 128,
                                  eW1 + 2*272*128, eb1 + 256,
                                  h, hbf, agg, A, xA, out, meanw,
                                  erec, units, ucnt + 2);
  // layer 2: edges from xA geometry, accumulate into out (seeded = xA - mean)
  k_edge<<<256, 512, EDGE_SMEM, stream>>>(out, A, hbf, erec, units, ucnt + 2,
                                          agg, pk + 2*PK_L, eb2 + 256, cb1 + 256, cW2 + 256);
}